// Round 6
// baseline (149.872 us; speedup 1.0000x reference)
//
#include <hip/hip_runtime.h>

typedef _Float16 half8 __attribute__((ext_vector_type(8)));
typedef _Float16 half4_t __attribute__((ext_vector_type(4)));
typedef float floatx4 __attribute__((ext_vector_type(4)));

// LDS tile: 64 rows x 128 halves (256 B rows). XOR swizzle on 16B-slot index:
// slot ^= (row & 7)  <=>  half-col ^= (row&7)<<3. Self-inverse involution,
// applied identically on the (pre-swizzled) global_load_lds source and on
// every ds_read / ds_write -> conflict-free and consistent (rule 21).
__device__ __forceinline__ int swz(int row, int col) {
    return row * 128 + (col ^ ((row & 7) << 3));
}

// Prep: blocks [0,96) repack W1/W2 to MFMA A-frag order (fp16);
// block 96 packs fp32 params [b1(128) | W1[:,0](128) | b2(64) | W3(64)];
// blocks [97,..) convert x to fp16 (xh = L2/L3-resident 6.4 MB copy).
__global__ __launch_bounds__(256) void prep_kernel(
    const float* __restrict__ x,
    const float* __restrict__ W1, const float* __restrict__ W2,
    const float* __restrict__ b1, const float* __restrict__ b2,
    const float* __restrict__ W3,
    _Float16* __restrict__ wsh, float* __restrict__ pf,
    _Float16* __restrict__ xh, int n_x8)
{
    int b = blockIdx.x;
    if (b < 96) {
        int tid = b * 256 + threadIdx.x;
        if (tid < 16384) {                    // W1 cols 1..128: 8 mtiles x 4 kb x 512
            int c = tid >> 9, r = tid & 511;
            int L = r >> 3, jj = r & 7;
            int mt = c >> 2, kb = c & 3;
            int n = mt * 16 + (L & 15);
            int k = kb * 32 + (L >> 4) * 8 + jj;
            wsh[tid] = (_Float16)W1[n * 129 + 1 + k];
        } else {                              // W2: 4 itiles x 4 kb x 512
            int t = tid - 16384;
            int c = t >> 9, r = t & 511;
            int L = r >> 3, jj = r & 7;
            int it = c >> 2, kb = c & 3;
            int i = it * 16 + (L & 15);
            int j = kb * 32 + (L >> 4) * 8 + jj;
            wsh[tid] = (_Float16)W2[i * 128 + j];
        }
    } else if (b == 96) {
        for (int i = threadIdx.x; i < 384; i += 256) {
            float v;
            if (i < 128)      v = b1[i];
            else if (i < 256) v = W1[(i - 128) * 129];   // W1[:,0]
            else if (i < 320) v = b2[i - 256];
            else              v = W3[i - 320];
            pf[i] = v;
        }
    } else {
        int t2 = (b - 97) * 256 + threadIdx.x;
        if (t2 < n_x8) {
            const float4* p = (const float4*)(x + (size_t)t2 * 8);
            float4 v0 = p[0], v1 = p[1];
            half8 h = {(_Float16)v0.x, (_Float16)v0.y, (_Float16)v0.z, (_Float16)v0.w,
                       (_Float16)v1.x, (_Float16)v1.y, (_Float16)v1.z, (_Float16)v1.w};
            *(half8*)(xh + (size_t)t2 * 8) = h;
        }
    }
}

// 64-edge tiles. DS-pipe traffic per block ~104 KB (was 216 KB in round 5):
//   gather-write 16K (global_load_lds, source pre-swizzled)
//   L1 reads 64K (bfr hoisted: loaded once per nt, reused for both mi)
//   h1 write 8K
//   L2 reads 16K (e-split: wave reads only its own 16 edges, once)
// LDS = 16 KB (hA only; s_out eliminated). 3 barriers (was 4).
__global__ __launch_bounds__(256, 4) void edge_mlp_kernel(
    const _Float16* __restrict__ xh,
    const int* __restrict__ ei,
    const float* __restrict__ ew,
    const float* __restrict__ b3,
    const _Float16* __restrict__ wf,
    const float* __restrict__ pf,
    float* __restrict__ out, int E)
{
    __shared__ __align__(16) _Float16 hA[64 * 128];   // feats, then h1 (aliased)

    const int tid  = threadIdx.x;
    const int lane = tid & 63;
    const int wave = tid >> 6;
    const int lrow = lane & 15;
    const int quad = lane >> 4;
    const int e_blk = blockIdx.x * 64;

    // ---- gather: direct global->LDS. Wave w, instr i covers rows
    // [w*16+i*4, +4). Lane l -> row += (l>>4), 16B-slot s = l&15. LDS is
    // written LINEARLY (base + lane*16); the swizzle is applied by choosing
    // the global source chunk c = s ^ (row&7): slot s ends up holding chunk
    // c, exactly what swz()-reads expect. c<8 -> src node, c>=8 -> tgt.
#pragma unroll
    for (int i = 0; i < 4; ++i) {
        int row = wave * 16 + i * 4 + quad;
        int c = lrow ^ (row & 7);
        int part = c >> 3;
        int e = e_blk + row; if (e >= E) e = E - 1;
        int node = ei[(size_t)part * E + e];
        const _Float16* g = xh + (size_t)node * 64 + (c & 7) * 8;
        __builtin_amdgcn_global_load_lds(
            (const __attribute__((address_space(1))) void*)g,
            (__attribute__((address_space(3))) void*)&hA[wave * 2048 + i * 512],
            16, 0, 0);
    }

    // ---- per-lane edge-weight prefetch (L1-broadcast) ----
    float ewv[4];
#pragma unroll
    for (int nt = 0; nt < 4; ++nt) {
        int e = e_blk + nt * 16 + lrow; if (e >= E) e = E - 1;
        ewv[nt] = ew[e];
    }
    const float b3v = b3[0];

    // persistent W1 A-frags: this wave's 2 m-tiles (32 VGPR)
    half8 afr[2][4];
#pragma unroll
    for (int mi = 0; mi < 2; ++mi)
#pragma unroll
        for (int kb = 0; kb < 4; ++kb)
            afr[mi][kb] = *(const half8*)(wf + ((2 * wave + mi) * 4 + kb) * 512 + lane * 8);

    __syncthreads();   // drains vmcnt(0): gather data landed in hA

    // ---- layer 1: nt-outer, bfr loaded ONCE and reused for both mi ----
    half4_t h1v[2][4];
#pragma unroll
    for (int nt = 0; nt < 4; ++nt) {
        int row = nt * 16 + lrow;
        half8 bfr[4];
#pragma unroll
        for (int kb = 0; kb < 4; ++kb)
            bfr[kb] = *(const half8*)(&hA[swz(row, kb * 32 + quad * 8)]);
#pragma unroll
        for (int mi = 0; mi < 2; ++mi) {
            floatx4 a = {0.f, 0.f, 0.f, 0.f};
#pragma unroll
            for (int kb = 0; kb < 4; ++kb)
                a = __builtin_amdgcn_mfma_f32_16x16x32_f16(afr[mi][kb], bfr[kb], a, 0, 0, 0);
            int nb = (2 * wave + mi) * 16 + quad * 4;
            float4 b1v = *(const float4*)(pf + nb);
            float4 c0v = *(const float4*)(pf + 128 + nb);
            half4_t hv;
            hv[0] = (_Float16)fmaxf(a[0] + b1v.x + ewv[nt] * c0v.x, 0.f);
            hv[1] = (_Float16)fmaxf(a[1] + b1v.y + ewv[nt] * c0v.y, 0.f);
            hv[2] = (_Float16)fmaxf(a[2] + b1v.z + ewv[nt] * c0v.z, 0.f);
            hv[3] = (_Float16)fmaxf(a[3] + b1v.w + ewv[nt] * c0v.w, 0.f);
            h1v[mi][nt] = hv;
        }
    }
    __syncthreads();   // all hA feature reads complete — safe to alias

    // ---- write hidden1 (fp16) into hA space as [e][n], swizzled ----
#pragma unroll
    for (int mi = 0; mi < 2; ++mi) {
        int nb = (2 * wave + mi) * 16 + quad * 4;
#pragma unroll
        for (int nt = 0; nt < 4; ++nt)
            *(half4_t*)(&hA[swz(nt * 16 + lrow, nb)]) = h1v[mi][nt];
    }
    __syncthreads();

    // ---- layer 2 (+fused layer 3), e-split: wave owns edges
    // [e_blk + wave*16, +16). Reads its h1 slice ONCE (4 KB) into regs,
    // streams W2 frags from global (16 KB region, L1-resident). Per-edge
    // total accumulates wave-locally: same order b3 + it0 + it1 + it2 + it3.
    const int erow = wave * 16 + lrow;
    half8 b2fr[4];
#pragma unroll
    for (int kb = 0; kb < 4; ++kb)
        b2fr[kb] = *(const half8*)(&hA[swz(erow, kb * 32 + quad * 8)]);

    float tot = b3v;
#pragma unroll
    for (int it = 0; it < 4; ++it) {
        half8 a2[4];
#pragma unroll
        for (int kb = 0; kb < 4; ++kb)
            a2[kb] = *(const half8*)(wf + 16384 + (it * 4 + kb) * 512 + lane * 8);
        int ib = it * 16 + quad * 4;
        float4 b2v = *(const float4*)(pf + 256 + ib);
        float4 w3v = *(const float4*)(pf + 320 + ib);
        floatx4 a = {0.f, 0.f, 0.f, 0.f};
#pragma unroll
        for (int kb = 0; kb < 4; ++kb)
            a = __builtin_amdgcn_mfma_f32_16x16x32_f16(a2[kb], b2fr[kb], a, 0, 0, 0);
        float p = fmaxf(a[0] + b2v.x, 0.f) * w3v.x;
        p      += fmaxf(a[1] + b2v.y, 0.f) * w3v.y;
        p      += fmaxf(a[2] + b2v.z, 0.f) * w3v.z;
        p      += fmaxf(a[3] + b2v.w, 0.f) * w3v.w;
        p += __shfl_xor(p, 16, 64);
        p += __shfl_xor(p, 32, 64);
        tot += p;
    }

    if (quad == 0) {
        int oe = e_blk + erow;
        if (oe < E) out[oe] = tot;
    }
}

extern "C" void kernel_launch(void* const* d_in, const int* in_sizes, int n_in,
                              void* d_out, int out_size, void* d_ws, size_t ws_size,
                              hipStream_t stream) {
    const float* x  = (const float*)d_in[0];
    const int*   ei = (const int*)d_in[1];   // int32 (verified round 1)
    const float* ew = (const float*)d_in[2];
    const float* W1 = (const float*)d_in[3];
    const float* b1 = (const float*)d_in[4];
    const float* W2 = (const float*)d_in[5];
    const float* b2 = (const float*)d_in[6];
    const float* W3 = (const float*)d_in[7];
    const float* b3 = (const float*)d_in[8];
    float* out = (float*)d_out;
    const int E = in_sizes[2];               // n_edges
    const int n_x = in_sizes[0];             // 3.2M floats
    const int n_x8 = n_x / 8;

    _Float16* wsh = (_Float16*)d_ws;                  // 24576 halves = 48 KiB
    float*    pf  = (float*)((char*)d_ws + 49152);    // 384 fp32 params
    _Float16* xh  = (_Float16*)((char*)d_ws + 51200); // fp16 x copy, 6.4 MB

    int xblk = (n_x8 + 255) / 256;
    prep_kernel<<<97 + xblk, 256, 0, stream>>>(x, W1, W2, b1, b2, W3,
                                               wsh, pf, xh, n_x8);

    int nblk = (E + 63) / 64;
    edge_mlp_kernel<<<nblk, 256, 0, stream>>>(xh, ei, ew, b3, wsh, pf, out, E);
}